// Round 20
// baseline (148.762 us; speedup 1.0000x reference)
//
#include <hip/hip_runtime.h>
#include <hip/hip_bf16.h>
#include <cstdint>
#include <cmath>

typedef __attribute__((ext_vector_type(8))) __bf16 bf16x8;
typedef __attribute__((ext_vector_type(8))) _Float16 f16x8;
typedef __attribute__((ext_vector_type(4))) float f32x4;
typedef __attribute__((ext_vector_type(16))) float f32x16;
typedef __attribute__((ext_vector_type(4))) int i32x4;
typedef __attribute__((ext_vector_type(16))) int i32x16;
typedef __attribute__((ext_vector_type(2))) unsigned long long u64x2;

typedef const __attribute__((address_space(1))) void* as1cvp;
typedef __attribute__((address_space(3))) void* as3vp;

__device__ __forceinline__ void gload_lds16(const void* g, void* l) {
  __builtin_amdgcn_global_load_lds((as1cvp)g, (as3vp)l, 16, 0, 0);
}
__device__ __forceinline__ float readlane_f(float v, int l) {
  return __uint_as_float((uint32_t)__builtin_amdgcn_readlane((int)__float_as_uint(v), l));
}

// K/V quantization scale; S_exp2 = (i32 dot) * C1 - SMBIAS
#define QS     (3.9f / 127.0f)
#define INVQS  (127.0f / 3.9f)
#define C1     (QS * QS * 0.12751706f)   // QS^2 * 128^-0.5 * log2(e)
#define SMBIAS 12.0f                      // keeps p = 2^(S-12) inside f16 range

// u8 V -> f16 (1024+u) dequant: f16 bits = 0x6400 | u, exact. 4 v_perm per 8 bytes.
__device__ __forceinline__ f16x8 dq8(uint64_t v) {
  union { uint32_t u[4]; f16x8 h; } r;
  uint32_t lo = (uint32_t)v, hi = (uint32_t)(v >> 32);
  r.u[0] = __builtin_amdgcn_perm(0x64646464u, lo, 0x04010400u);
  r.u[1] = __builtin_amdgcn_perm(0x64646464u, lo, 0x04030402u);
  r.u[2] = __builtin_amdgcn_perm(0x64646464u, hi, 0x04010400u);
  r.u[3] = __builtin_amdgcn_perm(0x64646464u, hi, 0x04030402u);
  return r.h;
}

// V^T t-permutation within each 32-block: new pos p -> old t offset.
__device__ __forceinline__ int vperm(int p) {
  return 16 * (p >> 4) + 4 * ((p >> 3) & 1) + 8 * ((p >> 2) & 1) + (p & 3);
}

// ---------------- Kernel 0: wk f32 -> bf16 (into d_out scratch) ----------------
__global__ __launch_bounds__(256) void wk_convert_kernel(
    const float* __restrict__ wk, __bf16* __restrict__ wkbf) {
  int i = (blockIdx.x * 256 + threadIdx.x) * 4;
  f32x4 v = *(const f32x4*)(wk + i);
  union { __bf16 e[4]; uint64_t u; } p;
#pragma unroll
  for (int j = 0; j < 4; j++) p.e[j] = (__bf16)v[j];
  *(uint64_t*)(wkbf + i) = p.u;
}

// ---------------- Kernel 1: K projection + RoPE, fragment-tiled outputs ----------------
// x: [32768][1024] f32 ; wkbf: [128][1024] bf16
// k2i8:  [1024 tiles][8 slot][32 kv][16] i8 (rotated K / QS; tile = 4KB)
// vt4u8: [1024 tiles][2 cp][128 d][16] u8 (pre-RoPE V / QS + 128, t-permuted; pair-packed:
//        bytes 0..7 = old chunk cp, bytes 8..15 = old chunk cp+2; tile = 4KB)
__global__ __launch_bounds__(256, 4) void proj_rope_kernel(
    const float* __restrict__ x, const __bf16* __restrict__ wkbf,
    char* __restrict__ k2i8, unsigned char* __restrict__ vt4u8)
{
  __shared__ __align__(16) char psmem[40960];
  const int tid = threadIdx.x;
  const int wid = tid >> 6;
  const int lane = tid & 63;
  const int m0 = blockIdx.x * 32;
  const int wn = wid * 32;

  f32x4 acc[2][2];
#pragma unroll
  for (int i = 0; i < 2; i++)
#pragma unroll
    for (int j = 0; j < 2; j++) acc[i][j] = (f32x4)0.f;

  const int ar = tid >> 3, ac = (tid & 7) * 8;
  const float* gx0 = x + (size_t)(m0 + ar) * 1024 + ac;

  f32x4 pa0, pa1;
#define LOADA(K0) do { const float* gp = gx0 + (K0); pa0 = *(const f32x4*)gp; pa1 = *(const f32x4*)(gp + 4); } while (0)
#define WRITEA(BUF) do { \
    bf16x8 av; \
    _Pragma("unroll") for (int jj = 0; jj < 4; jj++) { av[jj] = (__bf16)pa0[jj]; av[4 + jj] = (__bf16)pa1[jj]; } \
    *(bf16x8*)((__bf16*)psmem + (BUF) * 2048 + ar * 64 + (ac ^ ((ar & 7) << 3))) = av; \
  } while (0)
#define STAGEB(BUF, K0) do { \
    _Pragma("unroll") for (int h = 0; h < 4; h++) { \
      int Lc = tid + h * 256; int row = Lc >> 3, sp = Lc & 7; \
      gload_lds16((const char*)wkbf + row * 2048 + (K0) * 2 + ((sp ^ (row & 7)) << 4), \
                  psmem + 8192 + (BUF) * 16384 + Lc * 16); \
    } } while (0)

  LOADA(0);
  STAGEB(0, 0);
  WRITEA(0);
  __syncthreads();

  for (int t = 0; t < 16; t++) {
    const int buf = t & 1;
    const bool more = (t + 1 < 16);
    if (more) { LOADA((t + 1) * 64); STAGEB(buf ^ 1, (t + 1) * 64); }
    const __bf16* As = (const __bf16*)psmem + buf * 2048;
    const __bf16* Bs = (const __bf16*)(psmem + 8192 + buf * 16384);
#pragma unroll
    for (int kk = 0; kk < 2; kk++) {
      bf16x8 afr[2], bfr[2];
#pragma unroll
      for (int mi = 0; mi < 2; mi++) {
        int row = mi * 16 + (lane & 15);
        int col = (kk * 32 + (lane >> 4) * 8) ^ ((row & 7) << 3);
        afr[mi] = *(const bf16x8*)&As[row * 64 + col];
      }
#pragma unroll
      for (int ni = 0; ni < 2; ni++) {
        int row = wn + ni * 16 + (lane & 15);
        int col = (kk * 32 + (lane >> 4) * 8) ^ ((row & 7) << 3);
        bfr[ni] = *(const bf16x8*)&Bs[row * 64 + col];
      }
#pragma unroll
      for (int mi = 0; mi < 2; mi++)
#pragma unroll
        for (int ni = 0; ni < 2; ni++)
          acc[mi][ni] = __builtin_amdgcn_mfma_f32_16x16x32_bf16(afr[mi], bfr[ni], acc[mi][ni], 0, 0, 0);
    }
    if (more) WRITEA(buf ^ 1);
    __syncthreads();
  }

  // epilogue: RoPE; stage V (vl8, u8) and quantized K (kl8, i8, chunk-swizzled) in LDS
  float cosv[2], sinv[2];
#pragma unroll
  for (int ni = 0; ni < 2; ni++) {
    int d = wn + ni * 16 + (lane & 15);
    float theta = exp2f((float)(d >> 1) * -0.20762050593046014f); // 10000^(-i/64)
    cosv[ni] = cosf(theta);
    sinv[ni] = sinf(theta);
  }
  unsigned char* vl8 = (unsigned char*)psmem;  // [32][128] u8
  char* kl8 = psmem + 8192;                    // [32][128] i8, 16B-chunk c -> c ^ (row&7)
  const bool evenlane = ((lane & 1) == 0);
#pragma unroll
  for (int mi = 0; mi < 2; mi++) {
#pragma unroll
    for (int r = 0; r < 4; r++) {
      int ml = mi * 16 + (lane >> 4) * 4 + r;
#pragma unroll
      for (int ni = 0; ni < 2; ni++) {
        float val = acc[mi][ni][r];
        int d = wn + ni * 16 + (lane & 15);
        int uv = (int)lrintf(fminf(fmaxf(val * INVQS, -127.f), 127.f)) + 128;
        vl8[ml * 128 + d] = (unsigned char)uv;     // V = pre-RoPE k, quantized u8
        float partner = __shfl_xor(val, 1);
        float e = evenlane ? val : partner;
        float o = evenlane ? partner : val;
        float ev = e * cosv[ni] + o * sinv[ni];
        float od = -ev * sinv[ni] + o * cosv[ni];  // in-place slice semantics
        float kr = evenlane ? ev : od;
        int qv = (int)lrintf(fminf(fmaxf(kr * INVQS, -127.f), 127.f));
        kl8[ml * 128 + (((d >> 4) ^ (ml & 7)) << 4) + (d & 15)] = (char)qv;
      }
    }
  }
  __syncthreads();
  const size_t T = blockIdx.x;
  {
    // K out: k2i8[T][s][kv][16], d = 16s + byte
    int s = tid >> 5, kv = tid & 31;
    i32x4 w = *(const i32x4*)(kl8 + kv * 128 + ((s ^ (kv & 7)) << 4));
    *(i32x4*)(k2i8 + T * 4096 + s * 512 + kv * 16) = w;
  }
  {
    // V out: vt4u8[T][cp][d][16]: lower 8B = old chunk cp, upper 8B = old chunk cp+2
    int d = tid >> 1, th = tid & 1;   // cp = th
    union { unsigned char b[16]; i32x4 q; } w;
#pragma unroll
    for (int jj = 0; jj < 8; jj++) {
      w.b[jj]     = vl8[vperm(th * 8 + jj) * 128 + d];
      w.b[8 + jj] = vl8[vperm((th + 2) * 8 + jj) * 128 + d];
    }
    *(i32x4*)(vt4u8 + T * 4096 + th * 2048 + d * 16) = w.q;
  }
}

// ---------------- Kernel 2: causal flash attention, i8 QK + u8->f16 PV ----------------
// Block = 384 thr = 6 waves = 2 q-subtiles x 3-way kv split. Grid 512 = 2 blocks/CU
// = 12 waves/CU = 3 waves/SIMD (register cap 170 via launch_bounds). Pass 1: tiles
// {2G, 2G+1}; pass 2: {126-2G, 127-2G} -> per-block cost 258, G-independent.
__global__ __launch_bounds__(384, 3) void attn_kernel(
    const char* __restrict__ k2i8, const unsigned char* __restrict__ vt4u8,
    float* __restrict__ out)
{
  __shared__ __align__(16) char smem[66048]; // m[2 subs][2 slots][32][128] f32 + lbuf[2][2][32]
  const int tid = threadIdx.x;
  const int wid = tid >> 6;                     // 0..5
  const int sub = (wid >= 3) ? 1 : 0;           // q-subtile
  const int sp = wid - 3 * sub;                 // kv split (0..2)
  const int lane = tid & 63;
  const int lo5 = lane & 31;
  const int hi = lane >> 5;
  const int b = blockIdx.x & 7;                 // batch -> XCD (K/V L2-resident)
  const int G = (int)(blockIdx.x >> 3);         // 0..63
  const char* kt8 = k2i8 + (size_t)b * 524288;            // 128 tiles x 4KB
  const unsigned char* vb8 = vt4u8 + (size_t)b * 524288;  // 128 tiles x 4KB
  float* ob = out + (size_t)b * 4096 * 128;

  float* m0s = (float*)(smem + sub * 32768);          // slot 0: [32][128]
  float* m1s = (float*)(smem + sub * 32768 + 16384);  // slot 1
  float* lbuf = (float*)(smem + 65536) + sub * 64;    // [2][32]

#pragma unroll 1
  for (int pass = 0; pass < 2; pass++) {
    const int qt = pass ? (126 - 2 * G + sub) : (2 * G + sub);
    const int q0 = qt * 32;
    const int jd = qt;

    // Q fragments (i8): q row = lo5; MFMA ks covers d in [32ks,32ks+32), slot 2ks+hi
    i32x4 qf8[4];
    {
      const char* qp = kt8 + (size_t)qt * 4096 + lo5 * 16;
#pragma unroll
      for (int ks = 0; ks < 4; ks++) qf8[ks] = *(const i32x4*)(qp + (2 * ks + hi) * 512);
    }

    f32x16 acc[4];
#pragma unroll
    for (int dt = 0; dt < 4; dt++) acc[dt] = (f32x16)0.f;
    float l_r = 0.f;

    for (int j = sp; j <= jd; j += 3) {
      const char* kp8 = kt8 + (size_t)j * 4096 + lo5 * 16;
      const unsigned char* vp8 = vb8 + (size_t)j * 4096 + hi * 2048 + lo5 * 16;
      i32x4 kf8[4];
#pragma unroll
      for (int ks = 0; ks < 4; ks++) kf8[ks] = *(const i32x4*)(kp8 + (2 * ks + hi) * 512);
      u64x2 vu[4];
#pragma unroll
      for (int dt = 0; dt < 4; dt++) vu[dt] = *(const u64x2*)(vp8 + dt * 512);
      // QK^T (swapped, i8): S^T[kv][q], col=lo5=q, kv=(r&3)+8*(r>>2)+4*hi; single lean chain
      i32x16 Si = (i32x16)0;
      __builtin_amdgcn_s_setprio(1);
      Si = __builtin_amdgcn_mfma_i32_32x32x32_i8(kf8[0], qf8[0], Si, 0, 0, 0);
      Si = __builtin_amdgcn_mfma_i32_32x32x32_i8(kf8[1], qf8[1], Si, 0, 0, 0);
      Si = __builtin_amdgcn_mfma_i32_32x32x32_i8(kf8[2], qf8[2], Si, 0, 0, 0);
      Si = __builtin_amdgcn_mfma_i32_32x32x32_i8(kf8[3], qf8[3], Si, 0, 0, 0);
      __builtin_amdgcn_s_setprio(0);
      f32x16 S;
#pragma unroll
      for (int r = 0; r < 16; r++)
        S[r] = fmaf((float)Si[r], C1, -SMBIAS);
      if (j == jd) {
        const int kv0 = j * 32;
#pragma unroll
        for (int r = 0; r < 16; r++) {
          int kvg = kv0 + (r & 3) + 8 * (r >> 2) + 4 * hi;
          if (kvg > q0 + lo5) S[r] = -1e30f;
        }
      }
      // fixed-max softmax: p = exp2(S) in f16; lane-local l
      union U { _Float16 e[8]; f16x8 v; };
      U pk0, pk1;
      float rs = 0.f;
#pragma unroll
      for (int jj = 0; jj < 8; jj++) { float p = exp2f(S[jj]); rs += p; pk0.e[jj] = (_Float16)p; }
#pragma unroll
      for (int jj = 0; jj < 8; jj++) { float p = exp2f(S[8 + jj]); rs += p; pk1.e[jj] = (_Float16)p; }
      l_r += rs;
      // PV (f16): V dequant u8 -> f16(1024+u) via v_perm; offsets folded into epilogue
      __builtin_amdgcn_s_setprio(1);
#pragma unroll
      for (int dt = 0; dt < 4; dt++)
        acc[dt] = __builtin_amdgcn_mfma_f32_32x32x16_f16(pk0.v, dq8(vu[dt].x), acc[dt], 0, 0, 0);
#pragma unroll
      for (int dt = 0; dt < 4; dt++)
        acc[dt] = __builtin_amdgcn_mfma_f32_32x32x16_f16(pk1.v, dq8(vu[dt].y), acc[dt], 0, 0, 0);
      __builtin_amdgcn_s_setprio(0);
    }
    l_r += __shfl_xor(l_r, 32);

    // merge 3 kv-splits per sub (pure sums): sp1->slot0, sp2->slot1; sp0 += both; store.
#define ACC_TO(M) do { \
      _Pragma("unroll") for (int r = 0; r < 16; r++) { \
        int ql_ = (r & 3) + 8 * (r >> 2) + 4 * hi; \
        _Pragma("unroll") for (int dt = 0; dt < 4; dt++) (M)[ql_ * 128 + dt * 32 + lo5] = acc[dt][r]; } \
    } while (0)
#define ACC_ADD2(MA, MB) do { \
      _Pragma("unroll") for (int r = 0; r < 16; r++) { \
        int ql_ = (r & 3) + 8 * (r >> 2) + 4 * hi; \
        _Pragma("unroll") for (int dt = 0; dt < 4; dt++) \
          acc[dt][r] += (MA)[ql_ * 128 + dt * 32 + lo5] + (MB)[ql_ * 128 + dt * 32 + lo5]; } \
    } while (0)
    if (sp == 1) { ACC_TO(m0s); if (lane < 32) lbuf[lane] = l_r; }
    if (sp == 2) { ACC_TO(m1s); if (lane < 32) lbuf[32 + lane] = l_r; }
    __syncthreads();
    if (sp == 0) {
      ACC_ADD2(m0s, m1s);
      l_r += lbuf[lo5] + lbuf[32 + lo5];
      float invl = 1.0f / l_r;
#pragma unroll
      for (int r = 0; r < 16; r++) {
        const int rb = (r & 3) + 8 * (r >> 2);
        float ivr = hi ? readlane_f(invl, rb + 4) : readlane_f(invl, rb);
        const int ql = rb + 4 * hi;
        const size_t qg = (size_t)(q0 + ql);
#pragma unroll
        for (int dt = 0; dt < 4; dt++)
          ob[qg * 128 + dt * 32 + lo5] = (acc[dt][r] * ivr - 1152.0f) * QS;  // -(1024+128)
      }
    }
    __syncthreads();   // merge buffers free for next pass
  }
}

extern "C" void kernel_launch(void* const* d_in, const int* in_sizes, int n_in,
                              void* d_out, int out_size, void* d_ws, size_t ws_size,
                              hipStream_t stream) {
  const float* x  = (const float*)d_in[0];
  const float* wk = (const float*)d_in[1];
  char* k2i8 = (char*)d_ws;                                          // 4 MB, i8 K
  unsigned char* vt4u8 = (unsigned char*)d_ws + (size_t)4 * 1024 * 1024; // 4 MB, u8 V
  float* out   = (float*)d_out;
  __bf16* wkbf = (__bf16*)d_out;                                     // 256 KB scratch
  wk_convert_kernel<<<128, 256, 0, stream>>>(wk, wkbf);
  proj_rope_kernel<<<1024, 256, 0, stream>>>(x, wkbf, k2i8, vt4u8);
  attn_kernel<<<512, 384, 0, stream>>>(k2i8, vt4u8, out);
}

// Round 21
// 104.434 us; speedup vs baseline: 1.4245x; 1.4245x over previous
//
#include <hip/hip_runtime.h>
#include <hip/hip_bf16.h>
#include <cstdint>
#include <cmath>

typedef __attribute__((ext_vector_type(8))) __bf16 bf16x8;
typedef __attribute__((ext_vector_type(8))) _Float16 f16x8;
typedef __attribute__((ext_vector_type(4))) float f32x4;
typedef __attribute__((ext_vector_type(16))) float f32x16;
typedef __attribute__((ext_vector_type(4))) int i32x4;
typedef __attribute__((ext_vector_type(16))) int i32x16;
typedef __attribute__((ext_vector_type(2))) unsigned long long u64x2;

typedef const __attribute__((address_space(1))) void* as1cvp;
typedef __attribute__((address_space(3))) void* as3vp;

__device__ __forceinline__ void gload_lds16(const void* g, void* l) {
  __builtin_amdgcn_global_load_lds((as1cvp)g, (as3vp)l, 16, 0, 0);
}
__device__ __forceinline__ float readlane_f(float v, int l) {
  return __uint_as_float((uint32_t)__builtin_amdgcn_readlane((int)__float_as_uint(v), l));
}

// K/V quantization scale; S_exp2 = (i32 dot) * C1 - SMBIAS
#define QS     (3.9f / 127.0f)
#define INVQS  (127.0f / 3.9f)
#define C1     (QS * QS * 0.12751706f)   // QS^2 * 128^-0.5 * log2(e)
#define SMBIAS 12.0f                      // keeps p = 2^(S-12) inside f16 range

// u8 V -> f16 (1024+u) dequant: f16 bits = 0x6400 | u, exact. 4 v_perm per 8 bytes.
__device__ __forceinline__ f16x8 dq8(uint64_t v) {
  union { uint32_t u[4]; f16x8 h; } r;
  uint32_t lo = (uint32_t)v, hi = (uint32_t)(v >> 32);
  r.u[0] = __builtin_amdgcn_perm(0x64646464u, lo, 0x04010400u);
  r.u[1] = __builtin_amdgcn_perm(0x64646464u, lo, 0x04030402u);
  r.u[2] = __builtin_amdgcn_perm(0x64646464u, hi, 0x04010400u);
  r.u[3] = __builtin_amdgcn_perm(0x64646464u, hi, 0x04030402u);
  return r.h;
}

// V^T t-permutation within each 32-block: new pos p -> old t offset.
__device__ __forceinline__ int vperm(int p) {
  return 16 * (p >> 4) + 4 * ((p >> 3) & 1) + 8 * ((p >> 2) & 1) + (p & 3);
}

// ---------------- Kernel 0: wk f32 -> bf16 (into d_out scratch) ----------------
__global__ __launch_bounds__(256) void wk_convert_kernel(
    const float* __restrict__ wk, __bf16* __restrict__ wkbf) {
  int i = (blockIdx.x * 256 + threadIdx.x) * 4;
  f32x4 v = *(const f32x4*)(wk + i);
  union { __bf16 e[4]; uint64_t u; } p;
#pragma unroll
  for (int j = 0; j < 4; j++) p.e[j] = (__bf16)v[j];
  *(uint64_t*)(wkbf + i) = p.u;
}

// ---------------- Kernel 1: K projection + RoPE, fragment-tiled outputs ----------------
// x: [32768][1024] f32 ; wkbf: [128][1024] bf16
// k2i8:  [1024 tiles][8 slot][32 kv][16] i8 (rotated K / QS; tile = 4KB)
// vt4u8: [1024 tiles][2 cp][128 d][16] u8 (pre-RoPE V / QS + 128, t-permuted; pair-packed:
//        bytes 0..7 = old chunk cp, bytes 8..15 = old chunk cp+2; tile = 4KB)
__global__ __launch_bounds__(256, 4) void proj_rope_kernel(
    const float* __restrict__ x, const __bf16* __restrict__ wkbf,
    char* __restrict__ k2i8, unsigned char* __restrict__ vt4u8)
{
  __shared__ __align__(16) char psmem[40960];
  const int tid = threadIdx.x;
  const int wid = tid >> 6;
  const int lane = tid & 63;
  const int m0 = blockIdx.x * 32;
  const int wn = wid * 32;

  f32x4 acc[2][2];
#pragma unroll
  for (int i = 0; i < 2; i++)
#pragma unroll
    for (int j = 0; j < 2; j++) acc[i][j] = (f32x4)0.f;

  const int ar = tid >> 3, ac = (tid & 7) * 8;
  const float* gx0 = x + (size_t)(m0 + ar) * 1024 + ac;

  f32x4 pa0, pa1;
#define LOADA(K0) do { const float* gp = gx0 + (K0); pa0 = *(const f32x4*)gp; pa1 = *(const f32x4*)(gp + 4); } while (0)
#define WRITEA(BUF) do { \
    bf16x8 av; \
    _Pragma("unroll") for (int jj = 0; jj < 4; jj++) { av[jj] = (__bf16)pa0[jj]; av[4 + jj] = (__bf16)pa1[jj]; } \
    *(bf16x8*)((__bf16*)psmem + (BUF) * 2048 + ar * 64 + (ac ^ ((ar & 7) << 3))) = av; \
  } while (0)
#define STAGEB(BUF, K0) do { \
    _Pragma("unroll") for (int h = 0; h < 4; h++) { \
      int Lc = tid + h * 256; int row = Lc >> 3, sp = Lc & 7; \
      gload_lds16((const char*)wkbf + row * 2048 + (K0) * 2 + ((sp ^ (row & 7)) << 4), \
                  psmem + 8192 + (BUF) * 16384 + Lc * 16); \
    } } while (0)

  LOADA(0);
  STAGEB(0, 0);
  WRITEA(0);
  __syncthreads();

  for (int t = 0; t < 16; t++) {
    const int buf = t & 1;
    const bool more = (t + 1 < 16);
    if (more) { LOADA((t + 1) * 64); STAGEB(buf ^ 1, (t + 1) * 64); }
    const __bf16* As = (const __bf16*)psmem + buf * 2048;
    const __bf16* Bs = (const __bf16*)(psmem + 8192 + buf * 16384);
#pragma unroll
    for (int kk = 0; kk < 2; kk++) {
      bf16x8 afr[2], bfr[2];
#pragma unroll
      for (int mi = 0; mi < 2; mi++) {
        int row = mi * 16 + (lane & 15);
        int col = (kk * 32 + (lane >> 4) * 8) ^ ((row & 7) << 3);
        afr[mi] = *(const bf16x8*)&As[row * 64 + col];
      }
#pragma unroll
      for (int ni = 0; ni < 2; ni++) {
        int row = wn + ni * 16 + (lane & 15);
        int col = (kk * 32 + (lane >> 4) * 8) ^ ((row & 7) << 3);
        bfr[ni] = *(const bf16x8*)&Bs[row * 64 + col];
      }
#pragma unroll
      for (int mi = 0; mi < 2; mi++)
#pragma unroll
        for (int ni = 0; ni < 2; ni++)
          acc[mi][ni] = __builtin_amdgcn_mfma_f32_16x16x32_bf16(afr[mi], bfr[ni], acc[mi][ni], 0, 0, 0);
    }
    if (more) WRITEA(buf ^ 1);
    __syncthreads();
  }

  // epilogue: RoPE; stage V (vl8, u8) and quantized K (kl8, i8, chunk-swizzled) in LDS
  float cosv[2], sinv[2];
#pragma unroll
  for (int ni = 0; ni < 2; ni++) {
    int d = wn + ni * 16 + (lane & 15);
    float theta = exp2f((float)(d >> 1) * -0.20762050593046014f); // 10000^(-i/64)
    cosv[ni] = cosf(theta);
    sinv[ni] = sinf(theta);
  }
  unsigned char* vl8 = (unsigned char*)psmem;  // [32][128] u8
  char* kl8 = psmem + 8192;                    // [32][128] i8, 16B-chunk c -> c ^ (row&7)
  const bool evenlane = ((lane & 1) == 0);
#pragma unroll
  for (int mi = 0; mi < 2; mi++) {
#pragma unroll
    for (int r = 0; r < 4; r++) {
      int ml = mi * 16 + (lane >> 4) * 4 + r;
#pragma unroll
      for (int ni = 0; ni < 2; ni++) {
        float val = acc[mi][ni][r];
        int d = wn + ni * 16 + (lane & 15);
        int uv = (int)lrintf(fminf(fmaxf(val * INVQS, -127.f), 127.f)) + 128;
        vl8[ml * 128 + d] = (unsigned char)uv;     // V = pre-RoPE k, quantized u8
        float partner = __shfl_xor(val, 1);
        float e = evenlane ? val : partner;
        float o = evenlane ? partner : val;
        float ev = e * cosv[ni] + o * sinv[ni];
        float od = -ev * sinv[ni] + o * cosv[ni];  // in-place slice semantics
        float kr = evenlane ? ev : od;
        int qv = (int)lrintf(fminf(fmaxf(kr * INVQS, -127.f), 127.f));
        kl8[ml * 128 + (((d >> 4) ^ (ml & 7)) << 4) + (d & 15)] = (char)qv;
      }
    }
  }
  __syncthreads();
  const size_t T = blockIdx.x;
  {
    // K out: k2i8[T][s][kv][16], d = 16s + byte
    int s = tid >> 5, kv = tid & 31;
    i32x4 w = *(const i32x4*)(kl8 + kv * 128 + ((s ^ (kv & 7)) << 4));
    *(i32x4*)(k2i8 + T * 4096 + s * 512 + kv * 16) = w;
  }
  {
    // V out: vt4u8[T][cp][d][16]: lower 8B = old chunk cp, upper 8B = old chunk cp+2
    int d = tid >> 1, th = tid & 1;   // cp = th
    union { unsigned char b[16]; i32x4 q; } w;
#pragma unroll
    for (int jj = 0; jj < 8; jj++) {
      w.b[jj]     = vl8[vperm(th * 8 + jj) * 128 + d];
      w.b[8 + jj] = vl8[vperm((th + 2) * 8 + jj) * 128 + d];
    }
    *(i32x4*)(vt4u8 + T * 4096 + th * 2048 + d * 16) = w.q;
  }
}

// ---------------- Kernel 2: causal flash attention, i8 QK + u8->f16 PV ----------------
// Block = 384 thr = 6 waves = 6-way kv split over ONE 32-row q-tile per pass; passes
// qt=g then 127-g. Tile-reads per block-pass = tiles once (R18 traffic). Grid 512 =
// 2 blocks/CU = 12 waves/CU = 3 waves/SIMD (148 regs <= 170 cap).
__global__ __launch_bounds__(384, 3) void attn_kernel(
    const char* __restrict__ k2i8, const unsigned char* __restrict__ vt4u8,
    float* __restrict__ out)
{
  __shared__ __align__(16) char smem[49792]; // 3 slots x [32][128] f32 + lbuf[5][32]
  const int tid = threadIdx.x;
  const int sp = tid >> 6;                      // wave id = kv split (0..5)
  const int lane = tid & 63;
  const int lo5 = lane & 31;
  const int hi = lane >> 5;
  const int b = blockIdx.x & 7;                 // batch -> XCD (K/V L2-resident)
  const int g = (int)(blockIdx.x >> 3);         // 0..63
  const char* kt8 = k2i8 + (size_t)b * 524288;            // 128 tiles x 4KB
  const unsigned char* vb8 = vt4u8 + (size_t)b * 524288;  // 128 tiles x 4KB
  float* ob = out + (size_t)b * 4096 * 128;

  float* s0 = (float*)smem;                     // [32][128]
  float* s1 = (float*)(smem + 16384);
  float* s2 = (float*)(smem + 32768);
  float* lbuf = (float*)(smem + 49152);         // [5][32]

#pragma unroll 1
  for (int pass = 0; pass < 2; pass++) {
    const int qt = pass ? (127 - g) : g;        // two q-tiles, complementary cost
    const int q0 = qt * 32;
    const int jd = qt;

    // Q fragments (i8): q row = lo5; MFMA ks covers d in [32ks,32ks+32), slot 2ks+hi
    i32x4 qf8[4];
    {
      const char* qp = kt8 + (size_t)qt * 4096 + lo5 * 16;
#pragma unroll
      for (int ks = 0; ks < 4; ks++) qf8[ks] = *(const i32x4*)(qp + (2 * ks + hi) * 512);
    }

    f32x16 acc[4];
#pragma unroll
    for (int dt = 0; dt < 4; dt++) acc[dt] = (f32x16)0.f;
    float l_r = 0.f;

    for (int j = sp; j <= jd; j += 6) {
      const char* kp8 = kt8 + (size_t)j * 4096 + lo5 * 16;
      const unsigned char* vp8 = vb8 + (size_t)j * 4096 + hi * 2048 + lo5 * 16;
      i32x4 kf8[4];
#pragma unroll
      for (int ks = 0; ks < 4; ks++) kf8[ks] = *(const i32x4*)(kp8 + (2 * ks + hi) * 512);
      u64x2 vu[4];
#pragma unroll
      for (int dt = 0; dt < 4; dt++) vu[dt] = *(const u64x2*)(vp8 + dt * 512);
      // QK^T (swapped, i8): S^T[kv][q], col=lo5=q, kv=(r&3)+8*(r>>2)+4*hi; lean chain
      i32x16 Si = (i32x16)0;
      __builtin_amdgcn_s_setprio(1);
      Si = __builtin_amdgcn_mfma_i32_32x32x32_i8(kf8[0], qf8[0], Si, 0, 0, 0);
      Si = __builtin_amdgcn_mfma_i32_32x32x32_i8(kf8[1], qf8[1], Si, 0, 0, 0);
      Si = __builtin_amdgcn_mfma_i32_32x32x32_i8(kf8[2], qf8[2], Si, 0, 0, 0);
      Si = __builtin_amdgcn_mfma_i32_32x32x32_i8(kf8[3], qf8[3], Si, 0, 0, 0);
      __builtin_amdgcn_s_setprio(0);
      f32x16 S;
#pragma unroll
      for (int r = 0; r < 16; r++)
        S[r] = fmaf((float)Si[r], C1, -SMBIAS);
      if (j == jd) {
        const int kv0 = j * 32;
#pragma unroll
        for (int r = 0; r < 16; r++) {
          int kvg = kv0 + (r & 3) + 8 * (r >> 2) + 4 * hi;
          if (kvg > q0 + lo5) S[r] = -1e30f;
        }
      }
      // fixed-max softmax: p = exp2(S) in f16; lane-local l
      union U { _Float16 e[8]; f16x8 v; };
      U pk0, pk1;
      float rs = 0.f;
#pragma unroll
      for (int jj = 0; jj < 8; jj++) { float p = exp2f(S[jj]); rs += p; pk0.e[jj] = (_Float16)p; }
#pragma unroll
      for (int jj = 0; jj < 8; jj++) { float p = exp2f(S[8 + jj]); rs += p; pk1.e[jj] = (_Float16)p; }
      l_r += rs;
      // PV (f16): V dequant u8 -> f16(1024+u) via v_perm; offsets folded into epilogue
      __builtin_amdgcn_s_setprio(1);
#pragma unroll
      for (int dt = 0; dt < 4; dt++)
        acc[dt] = __builtin_amdgcn_mfma_f32_32x32x16_f16(pk0.v, dq8(vu[dt].x), acc[dt], 0, 0, 0);
#pragma unroll
      for (int dt = 0; dt < 4; dt++)
        acc[dt] = __builtin_amdgcn_mfma_f32_32x32x16_f16(pk1.v, dq8(vu[dt].y), acc[dt], 0, 0, 0);
      __builtin_amdgcn_s_setprio(0);
    }
    l_r += __shfl_xor(l_r, 32);

    // merge 6 kv-splits (pure sums), 2-stage tree:
    // stage1: 1->s0, 3->s1, 5->s2; 0+=s0, 2+=s1, 4+=s2
    // stage2: 2->s0, 4->s1; 0 += s0+s1; store.
#define ACC_TO(M) do { \
      _Pragma("unroll") for (int r = 0; r < 16; r++) { \
        int ql_ = (r & 3) + 8 * (r >> 2) + 4 * hi; \
        _Pragma("unroll") for (int dt = 0; dt < 4; dt++) (M)[ql_ * 128 + dt * 32 + lo5] = acc[dt][r]; } \
    } while (0)
#define ACC_ADD(M) do { \
      _Pragma("unroll") for (int r = 0; r < 16; r++) { \
        int ql_ = (r & 3) + 8 * (r >> 2) + 4 * hi; \
        _Pragma("unroll") for (int dt = 0; dt < 4; dt++) acc[dt][r] += (M)[ql_ * 128 + dt * 32 + lo5]; } \
    } while (0)
#define ACC_ADD2(MA, MB) do { \
      _Pragma("unroll") for (int r = 0; r < 16; r++) { \
        int ql_ = (r & 3) + 8 * (r >> 2) + 4 * hi; \
        _Pragma("unroll") for (int dt = 0; dt < 4; dt++) \
          acc[dt][r] += (MA)[ql_ * 128 + dt * 32 + lo5] + (MB)[ql_ * 128 + dt * 32 + lo5]; } \
    } while (0)
    if (sp == 1) { ACC_TO(s0); if (lane < 32) lbuf[lane] = l_r; }
    if (sp == 3) { ACC_TO(s1); if (lane < 32) lbuf[32 + lane] = l_r; }
    if (sp == 5) { ACC_TO(s2); if (lane < 32) lbuf[64 + lane] = l_r; }
    __syncthreads();
    if (sp == 0) { ACC_ADD(s0); l_r += lbuf[lo5]; }
    if (sp == 2) { ACC_ADD(s1); l_r += lbuf[32 + lo5]; }
    if (sp == 4) { ACC_ADD(s2); l_r += lbuf[64 + lo5]; }
    __syncthreads();
    if (sp == 2) { ACC_TO(s0); if (lane < 32) lbuf[96 + lane] = l_r; }
    if (sp == 4) { ACC_TO(s1); if (lane < 32) lbuf[128 + lane] = l_r; }
    __syncthreads();
    if (sp == 0) {
      ACC_ADD2(s0, s1);
      l_r += lbuf[96 + lo5] + lbuf[128 + lo5];
      float invl = 1.0f / l_r;
#pragma unroll
      for (int r = 0; r < 16; r++) {
        const int rb = (r & 3) + 8 * (r >> 2);
        float ivr = hi ? readlane_f(invl, rb + 4) : readlane_f(invl, rb);
        const int ql = rb + 4 * hi;
        const size_t qg = (size_t)(q0 + ql);
#pragma unroll
        for (int dt = 0; dt < 4; dt++)
          ob[qg * 128 + dt * 32 + lo5] = (acc[dt][r] * ivr - 1152.0f) * QS;  // -(1024+128)
      }
    }
    __syncthreads();   // merge buffers free for next pass
  }
}

extern "C" void kernel_launch(void* const* d_in, const int* in_sizes, int n_in,
                              void* d_out, int out_size, void* d_ws, size_t ws_size,
                              hipStream_t stream) {
  const float* x  = (const float*)d_in[0];
  const float* wk = (const float*)d_in[1];
  char* k2i8 = (char*)d_ws;                                          // 4 MB, i8 K
  unsigned char* vt4u8 = (unsigned char*)d_ws + (size_t)4 * 1024 * 1024; // 4 MB, u8 V
  float* out   = (float*)d_out;
  __bf16* wkbf = (__bf16*)d_out;                                     // 256 KB scratch
  wk_convert_kernel<<<128, 256, 0, stream>>>(wk, wkbf);
  proj_rope_kernel<<<1024, 256, 0, stream>>>(x, wkbf, k2i8, vt4u8);
  attn_kernel<<<512, 384, 0, stream>>>(k2i8, vt4u8, out);
}

// Round 22
// 85.655 us; speedup vs baseline: 1.7368x; 1.2192x over previous
//
#include <hip/hip_runtime.h>
#include <hip/hip_bf16.h>
#include <cstdint>
#include <cmath>

typedef __attribute__((ext_vector_type(8))) __bf16 bf16x8;
typedef __attribute__((ext_vector_type(8))) _Float16 f16x8;
typedef __attribute__((ext_vector_type(4))) float f32x4;
typedef __attribute__((ext_vector_type(16))) float f32x16;
typedef __attribute__((ext_vector_type(4))) int i32x4;
typedef __attribute__((ext_vector_type(16))) int i32x16;

typedef const __attribute__((address_space(1))) void* as1cvp;
typedef __attribute__((address_space(3))) void* as3vp;

__device__ __forceinline__ void gload_lds16(const void* g, void* l) {
  __builtin_amdgcn_global_load_lds((as1cvp)g, (as3vp)l, 16, 0, 0);
}
__device__ __forceinline__ float readlane_f(float v, int l) {
  return __uint_as_float((uint32_t)__builtin_amdgcn_readlane((int)__float_as_uint(v), l));
}

// K/V quantization scale; S_exp2 = (i32 dot) * C1 - SMBIAS
#define QS     (3.9f / 127.0f)
#define INVQS  (127.0f / 3.9f)
#define C1     (QS * QS * 0.12751706f)   // QS^2 * 128^-0.5 * log2(e)
#define SMBIAS 12.0f                      // keeps p = 2^(S-12) inside f16 range

// u8 V -> f16 (1024+u) dequant: f16 bits = 0x6400 | u, exact. 4 v_perm per 8 bytes.
__device__ __forceinline__ f16x8 dq8(uint64_t v) {
  union { uint32_t u[4]; f16x8 h; } r;
  uint32_t lo = (uint32_t)v, hi = (uint32_t)(v >> 32);
  r.u[0] = __builtin_amdgcn_perm(0x64646464u, lo, 0x04010400u);
  r.u[1] = __builtin_amdgcn_perm(0x64646464u, lo, 0x04030402u);
  r.u[2] = __builtin_amdgcn_perm(0x64646464u, hi, 0x04010400u);
  r.u[3] = __builtin_amdgcn_perm(0x64646464u, hi, 0x04030402u);
  return r.h;
}

// V^T t-permutation within each 32-block: new pos p -> old t offset.
__device__ __forceinline__ int vperm(int p) {
  return 16 * (p >> 4) + 4 * ((p >> 3) & 1) + 8 * ((p >> 2) & 1) + (p & 3);
}

// ---------------- Kernel 0: wk f32 -> bf16 (into d_out scratch) ----------------
__global__ __launch_bounds__(256) void wk_convert_kernel(
    const float* __restrict__ wk, __bf16* __restrict__ wkbf) {
  int i = (blockIdx.x * 256 + threadIdx.x) * 4;
  f32x4 v = *(const f32x4*)(wk + i);
  union { __bf16 e[4]; uint64_t u; } p;
#pragma unroll
  for (int j = 0; j < 4; j++) p.e[j] = (__bf16)v[j];
  *(uint64_t*)(wkbf + i) = p.u;
}

// ---------------- Kernel 1: K projection + RoPE, fragment-tiled outputs ----------------
// x: [32768][1024] f32 ; wkbf: [128][1024] bf16
// k2i8:  [1024 tiles][8 slot][32 kv][16] i8 (rotated K / QS; tile = 4KB)
// vt3u8: [1024 tiles][4 chunk][128 d][8] u8 (pre-RoPE V / QS + 128, t-permuted; tile = 4KB)
__global__ __launch_bounds__(256, 4) void proj_rope_kernel(
    const float* __restrict__ x, const __bf16* __restrict__ wkbf,
    char* __restrict__ k2i8, unsigned char* __restrict__ vt3u8)
{
  __shared__ __align__(16) char psmem[40960];
  const int tid = threadIdx.x;
  const int wid = tid >> 6;
  const int lane = tid & 63;
  const int m0 = blockIdx.x * 32;
  const int wn = wid * 32;

  f32x4 acc[2][2];
#pragma unroll
  for (int i = 0; i < 2; i++)
#pragma unroll
    for (int j = 0; j < 2; j++) acc[i][j] = (f32x4)0.f;

  const int ar = tid >> 3, ac = (tid & 7) * 8;
  const float* gx0 = x + (size_t)(m0 + ar) * 1024 + ac;

  f32x4 pa0, pa1;
#define LOADA(K0) do { const float* gp = gx0 + (K0); pa0 = *(const f32x4*)gp; pa1 = *(const f32x4*)(gp + 4); } while (0)
#define WRITEA(BUF) do { \
    bf16x8 av; \
    _Pragma("unroll") for (int jj = 0; jj < 4; jj++) { av[jj] = (__bf16)pa0[jj]; av[4 + jj] = (__bf16)pa1[jj]; } \
    *(bf16x8*)((__bf16*)psmem + (BUF) * 2048 + ar * 64 + (ac ^ ((ar & 7) << 3))) = av; \
  } while (0)
#define STAGEB(BUF, K0) do { \
    _Pragma("unroll") for (int h = 0; h < 4; h++) { \
      int Lc = tid + h * 256; int row = Lc >> 3, sp = Lc & 7; \
      gload_lds16((const char*)wkbf + row * 2048 + (K0) * 2 + ((sp ^ (row & 7)) << 4), \
                  psmem + 8192 + (BUF) * 16384 + Lc * 16); \
    } } while (0)

  LOADA(0);
  STAGEB(0, 0);
  WRITEA(0);
  __syncthreads();

  for (int t = 0; t < 16; t++) {
    const int buf = t & 1;
    const bool more = (t + 1 < 16);
    if (more) { LOADA((t + 1) * 64); STAGEB(buf ^ 1, (t + 1) * 64); }
    const __bf16* As = (const __bf16*)psmem + buf * 2048;
    const __bf16* Bs = (const __bf16*)(psmem + 8192 + buf * 16384);
#pragma unroll
    for (int kk = 0; kk < 2; kk++) {
      bf16x8 afr[2], bfr[2];
#pragma unroll
      for (int mi = 0; mi < 2; mi++) {
        int row = mi * 16 + (lane & 15);
        int col = (kk * 32 + (lane >> 4) * 8) ^ ((row & 7) << 3);
        afr[mi] = *(const bf16x8*)&As[row * 64 + col];
      }
#pragma unroll
      for (int ni = 0; ni < 2; ni++) {
        int row = wn + ni * 16 + (lane & 15);
        int col = (kk * 32 + (lane >> 4) * 8) ^ ((row & 7) << 3);
        bfr[ni] = *(const bf16x8*)&Bs[row * 64 + col];
      }
#pragma unroll
      for (int mi = 0; mi < 2; mi++)
#pragma unroll
        for (int ni = 0; ni < 2; ni++)
          acc[mi][ni] = __builtin_amdgcn_mfma_f32_16x16x32_bf16(afr[mi], bfr[ni], acc[mi][ni], 0, 0, 0);
    }
    if (more) WRITEA(buf ^ 1);
    __syncthreads();
  }

  // epilogue: RoPE; stage V (vl8, u8) and quantized K (kl8, i8, chunk-swizzled) in LDS
  float cosv[2], sinv[2];
#pragma unroll
  for (int ni = 0; ni < 2; ni++) {
    int d = wn + ni * 16 + (lane & 15);
    float theta = exp2f((float)(d >> 1) * -0.20762050593046014f); // 10000^(-i/64)
    cosv[ni] = cosf(theta);
    sinv[ni] = sinf(theta);
  }
  unsigned char* vl8 = (unsigned char*)psmem;  // [32][128] u8
  char* kl8 = psmem + 8192;                    // [32][128] i8, 16B-chunk c -> c ^ (row&7)
  const bool evenlane = ((lane & 1) == 0);
#pragma unroll
  for (int mi = 0; mi < 2; mi++) {
#pragma unroll
    for (int r = 0; r < 4; r++) {
      int ml = mi * 16 + (lane >> 4) * 4 + r;
#pragma unroll
      for (int ni = 0; ni < 2; ni++) {
        float val = acc[mi][ni][r];
        int d = wn + ni * 16 + (lane & 15);
        int uv = (int)lrintf(fminf(fmaxf(val * INVQS, -127.f), 127.f)) + 128;
        vl8[ml * 128 + d] = (unsigned char)uv;     // V = pre-RoPE k, quantized u8
        float partner = __shfl_xor(val, 1);
        float e = evenlane ? val : partner;
        float o = evenlane ? partner : val;
        float ev = e * cosv[ni] + o * sinv[ni];
        float od = -ev * sinv[ni] + o * cosv[ni];  // in-place slice semantics
        float kr = evenlane ? ev : od;
        int qv = (int)lrintf(fminf(fmaxf(kr * INVQS, -127.f), 127.f));
        kl8[ml * 128 + (((d >> 4) ^ (ml & 7)) << 4) + (d & 15)] = (char)qv;
      }
    }
  }
  __syncthreads();
  const size_t T = blockIdx.x;
  {
    // K out: k2i8[T][s][kv][16], d = 16s + byte
    int s = tid >> 5, kv = tid & 31;
    i32x4 w = *(const i32x4*)(kl8 + kv * 128 + ((s ^ (kv & 7)) << 4));
    *(i32x4*)(k2i8 + T * 4096 + s * 512 + kv * 16) = w;
  }
  {
    // V out: vt3u8[T][c][d][8], t-permuted
    int d = tid >> 1, th = tid & 1;
    unsigned char* vg = vt3u8 + T * 4096 + d * 8;
#pragma unroll
    for (int cc = 0; cc < 2; cc++) {
      int c = 2 * th + cc;
      union { unsigned char b[8]; uint64_t u; } w;
#pragma unroll
      for (int jj = 0; jj < 8; jj++)
        w.b[jj] = vl8[vperm(c * 8 + jj) * 128 + d];
      *(uint64_t*)(vg + c * 1024) = w.u;
    }
  }
}

// ---------------- Kernel 2: causal flash attention, i8 QK + u8->f16 PV, paired q-tiles ----------------
// Block = 4 waves = 4-way kv split over ONE 32-row q-tile; passes qt=g then qt=127-g.
// Grid 512 = 2 blocks/CU. K tile 4KB (i8) + V tile 4KB (u8) -> 8KB/visit ingress.
__global__ __launch_bounds__(256) void attn_kernel(
    const char* __restrict__ k2i8, const unsigned char* __restrict__ vt3u8,
    float* __restrict__ out)
{
  __shared__ __align__(16) char smem[33152]; // mA[32][128]f32 | mB | lbuf[3][32]
  const int tid = threadIdx.x;
  const int split = tid >> 6;                   // wave id = kv split (0..3)
  const int lane = tid & 63;
  const int lo5 = lane & 31;
  const int hi = lane >> 5;
  const int b = blockIdx.x & 7;                 // batch -> XCD (K/V L2-resident)
  const int g = (int)(blockIdx.x >> 3);         // 0..63
  const char* kt8 = k2i8 + (size_t)b * 524288;            // 128 tiles x 4KB
  const unsigned char* vb8 = vt3u8 + (size_t)b * 524288;  // 128 tiles x 4KB
  float* ob = out + (size_t)b * 4096 * 128;

  float* mA = (float*)smem;                     // [32 q][128 d]
  float* mB = (float*)(smem + 16384);
  float* lbuf = (float*)(smem + 32768);         // [3][32]

#pragma unroll 1
  for (int pass = 0; pass < 2; pass++) {
    const int qt = pass ? (127 - g) : g;        // two q-tiles, complementary cost
    const int q0 = qt * 32;
    const int jd = qt;

    // Q fragments (i8): q row = lo5; MFMA ks covers d in [32ks,32ks+32), slot 2ks+hi
    i32x4 qf8[4];
    {
      const char* qp = kt8 + (size_t)qt * 4096 + lo5 * 16;
#pragma unroll
      for (int ks = 0; ks < 4; ks++) qf8[ks] = *(const i32x4*)(qp + (2 * ks + hi) * 512);
    }

    f32x16 acc[4];
#pragma unroll
    for (int dt = 0; dt < 4; dt++) acc[dt] = (f32x16)0.f;
    float l_r = 0.f;

    for (int j = split; j <= jd; j += 4) {
      const char* kp8 = kt8 + (size_t)j * 4096 + lo5 * 16;
      const unsigned char* vp8 = vb8 + (size_t)j * 4096 + lo5 * 8;
      i32x4 kf8[4];
#pragma unroll
      for (int ks = 0; ks < 4; ks++) kf8[ks] = *(const i32x4*)(kp8 + (2 * ks + hi) * 512);
      uint64_t vu0[4], vu1[4];
#pragma unroll
      for (int dt = 0; dt < 4; dt++) {
        vu0[dt] = *(const uint64_t*)(vp8 + hi * 1024 + dt * 256);
        vu1[dt] = *(const uint64_t*)(vp8 + (2 + hi) * 1024 + dt * 256);
      }
      // QK^T (swapped, i8): S^T[kv][q], col=lo5=q, kv=(r&3)+8*(r>>2)+4*hi; dual chain
      i32x16 S0i = (i32x16)0, S1i = (i32x16)0;
      __builtin_amdgcn_s_setprio(1);
      S0i = __builtin_amdgcn_mfma_i32_32x32x32_i8(kf8[0], qf8[0], S0i, 0, 0, 0);
      S0i = __builtin_amdgcn_mfma_i32_32x32x32_i8(kf8[1], qf8[1], S0i, 0, 0, 0);
      S1i = __builtin_amdgcn_mfma_i32_32x32x32_i8(kf8[2], qf8[2], S1i, 0, 0, 0);
      S1i = __builtin_amdgcn_mfma_i32_32x32x32_i8(kf8[3], qf8[3], S1i, 0, 0, 0);
      __builtin_amdgcn_s_setprio(0);
      f32x16 S;
#pragma unroll
      for (int r = 0; r < 16; r++)
        S[r] = fmaf((float)(S0i[r] + S1i[r]), C1, -SMBIAS);
      if (j == jd) {
        const int kv0 = j * 32;
#pragma unroll
        for (int r = 0; r < 16; r++) {
          int kvg = kv0 + (r & 3) + 8 * (r >> 2) + 4 * hi;
          if (kvg > q0 + lo5) S[r] = -1e30f;
        }
      }
      // fixed-max softmax: p = exp2(S) in f16; lane-local l
      union U { _Float16 e[8]; f16x8 v; };
      U pk0, pk1;
      float rs = 0.f;
#pragma unroll
      for (int jj = 0; jj < 8; jj++) { float p = exp2f(S[jj]); rs += p; pk0.e[jj] = (_Float16)p; }
#pragma unroll
      for (int jj = 0; jj < 8; jj++) { float p = exp2f(S[8 + jj]); rs += p; pk1.e[jj] = (_Float16)p; }
      l_r += rs;
      // PV (f16): V dequant u8 -> f16(1024+u) via v_perm; offsets folded into epilogue
      __builtin_amdgcn_s_setprio(1);
#pragma unroll
      for (int dt = 0; dt < 4; dt++)
        acc[dt] = __builtin_amdgcn_mfma_f32_32x32x16_f16(pk0.v, dq8(vu0[dt]), acc[dt], 0, 0, 0);
#pragma unroll
      for (int dt = 0; dt < 4; dt++)
        acc[dt] = __builtin_amdgcn_mfma_f32_32x32x16_f16(pk1.v, dq8(vu1[dt]), acc[dt], 0, 0, 0);
      __builtin_amdgcn_s_setprio(0);
    }
    l_r += __shfl_xor(l_r, 32);

    // merge 4 kv-splits (pure sums): 1->mA, 3->mB; 0+=mA, 2+=mB; 2->mA; 0+=mA; store.
#define ACC_TO(M) do { \
      _Pragma("unroll") for (int r = 0; r < 16; r++) { \
        int ql_ = (r & 3) + 8 * (r >> 2) + 4 * hi; \
        _Pragma("unroll") for (int dt = 0; dt < 4; dt++) (M)[ql_ * 128 + dt * 32 + lo5] = acc[dt][r]; } \
    } while (0)
#define ACC_ADD(M) do { \
      _Pragma("unroll") for (int r = 0; r < 16; r++) { \
        int ql_ = (r & 3) + 8 * (r >> 2) + 4 * hi; \
        _Pragma("unroll") for (int dt = 0; dt < 4; dt++) acc[dt][r] += (M)[ql_ * 128 + dt * 32 + lo5]; } \
    } while (0)
    if (split == 1) { ACC_TO(mA); if (lane < 32) lbuf[lane] = l_r; }
    if (split == 3) { ACC_TO(mB); if (lane < 32) lbuf[64 + lane] = l_r; }
    __syncthreads();
    if (split == 0) { ACC_ADD(mA); l_r += lbuf[lo5]; }
    if (split == 2) { ACC_ADD(mB); l_r += lbuf[64 + lo5]; }
    __syncthreads();
    if (split == 2) { ACC_TO(mA); if (lane < 32) lbuf[32 + lane] = l_r; }
    __syncthreads();
    if (split == 0) {
      ACC_ADD(mA);
      l_r += lbuf[32 + lo5];
      float invl = 1.0f / l_r;
#pragma unroll
      for (int r = 0; r < 16; r++) {
        const int rb = (r & 3) + 8 * (r >> 2);
        float ivr = hi ? readlane_f(invl, rb + 4) : readlane_f(invl, rb);
        const int ql = rb + 4 * hi;
        const size_t qg = (size_t)(q0 + ql);
#pragma unroll
        for (int dt = 0; dt < 4; dt++)
          ob[qg * 128 + dt * 32 + lo5] = (acc[dt][r] * ivr - 1152.0f) * QS;  // -(1024+128)
      }
    }
    __syncthreads();   // mA/mB/lbuf free for next pass
  }
}

extern "C" void kernel_launch(void* const* d_in, const int* in_sizes, int n_in,
                              void* d_out, int out_size, void* d_ws, size_t ws_size,
                              hipStream_t stream) {
  const float* x  = (const float*)d_in[0];
  const float* wk = (const float*)d_in[1];
  char* k2i8 = (char*)d_ws;                                          // 4 MB, i8 K
  unsigned char* vt3u8 = (unsigned char*)d_ws + (size_t)4 * 1024 * 1024; // 4 MB, u8 V
  float* out   = (float*)d_out;
  __bf16* wkbf = (__bf16*)d_out;                                     // 256 KB scratch
  wk_convert_kernel<<<128, 256, 0, stream>>>(wk, wkbf);
  proj_rope_kernel<<<1024, 256, 0, stream>>>(x, wkbf, k2i8, vt3u8);
  attn_kernel<<<512, 256, 0, stream>>>(k2i8, vt3u8, out);
}